// Round 1
// baseline (402.798 us; speedup 1.0000x reference)
//
#include <hip/hip_runtime.h>
#include <stdint.h>

#define NTOK 65536     // B*S = 16*4096
#define DMODEL 512
#define QKVN 1536
#define LN_EPS 1e-5f

typedef __attribute__((ext_vector_type(8))) short short8;
typedef __attribute__((ext_vector_type(8))) unsigned short ushort8;
typedef __attribute__((ext_vector_type(4))) float float4_t;

static __device__ __forceinline__ float bf2f(unsigned short u) {
    union { unsigned int i; float f; } c; c.i = ((unsigned int)u) << 16; return c.f;
}
static __device__ __forceinline__ unsigned short f2bf(float f) {
    union { float f; unsigned int i; } c; c.f = f;
    unsigned int x = c.i;
    return (unsigned short)((x + 0x7fffu + ((x >> 16) & 1u)) >> 16);  // RNE
}
static __device__ __forceinline__ void gload_lds16(const void* g, void* l) {
    __builtin_amdgcn_global_load_lds((const __attribute__((address_space(1))) void*)g,
                                     (__attribute__((address_space(3))) void*)l, 16, 0, 0);
}

// ---------------------------------------------------------------- prep: cast x to bf16
__global__ __launch_bounds__(256) void cast_x_kernel(const float* __restrict__ x,
                                                     unsigned short* __restrict__ xb, int n8) {
    int stride = gridDim.x * blockDim.x;
    for (int i = blockIdx.x * blockDim.x + threadIdx.x; i < n8; i += stride) {
        const float4_t* p = (const float4_t*)(x + (size_t)i * 8);
        float4_t a = p[0], b = p[1];
        ushort8 v;
        v[0] = f2bf(a[0]); v[1] = f2bf(a[1]); v[2] = f2bf(a[2]); v[3] = f2bf(a[3]);
        v[4] = f2bf(b[0]); v[5] = f2bf(b[1]); v[6] = f2bf(b[2]); v[7] = f2bf(b[3]);
        *(ushort8*)(xb + (size_t)i * 8) = v;
    }
}

// ---------------------------------------------------------------- prep: weights + bias
__global__ __launch_bounds__(256) void prep_w_kernel(
    const float* __restrict__ wq, const float* __restrict__ wk, const float* __restrict__ wv,
    const float* __restrict__ wo,
    const float* __restrict__ bq, const float* __restrict__ bk, const float* __restrict__ bv,
    unsigned short* __restrict__ wqkv, unsigned short* __restrict__ wob,
    float* __restrict__ bias_qkv) {
    const int WN = DMODEL * DMODEL;  // 262144
    int tid = blockIdx.x * blockDim.x + threadIdx.x;
    int stride = gridDim.x * blockDim.x;
    for (int j = tid; j < 3 * WN; j += stride) {
        int seg = j / WN, idx = j - seg * WN;
        const float* src = (seg == 0) ? wq : (seg == 1) ? wk : wv;
        wqkv[j] = f2bf(src[idx]);
    }
    for (int j = tid; j < WN; j += stride) wob[j] = f2bf(wo[j]);
    for (int j = tid; j < QKVN; j += stride)
        bias_qkv[j] = (j < 512) ? bq[j] : (j < 1024) ? bk[j - 512] : bv[j - 1024];
}

// ---------------------------------------------------------------- GEMM: C = A @ B^T + bias (+resid)
// A [M,512] bf16 row-major, Bw [N,512] bf16 row-major (K contiguous both).
// EPI=0: store bf16 C[M,N].  EPI=1: store fp32 C[M,N] = acc + bias + resid.
template <int EPI>
__global__ __launch_bounds__(256) void gemm_bt_kernel(
    const unsigned short* __restrict__ A, const unsigned short* __restrict__ Bw,
    const float* __restrict__ bias, const float* __restrict__ resid,
    void* __restrict__ Cout, int N) {
    __shared__ unsigned short As[128 * 32];
    __shared__ unsigned short Bs[128 * 32];

    const int nbn = N >> 7;
    const int bm = blockIdx.x / nbn;
    const int bn = blockIdx.x - bm * nbn;
    const int t = threadIdx.x;
    const int lane = t & 63;
    const int w = t >> 6;
    const int wm = w >> 1, wn = w & 1;

    float4_t acc[4][4];
#pragma unroll
    for (int m = 0; m < 4; m++)
#pragma unroll
        for (int n = 0; n < 4; n++) acc[m][n] = (float4_t){0.f, 0.f, 0.f, 0.f};

    const unsigned short* Abase = A + (size_t)bm * 128 * 512;
    const unsigned short* Bbase = Bw + (size_t)bn * 128 * 512;

    for (int k0 = 0; k0 < 512; k0 += 32) {
        // stage 128x32 bf16 tiles of A and B via async global->LDS (16B/lane)
#pragma unroll
        for (int c = 0; c < 2; ++c) {
            int idx = c * 256 + t;
            int row = idx >> 2;
            int kel = (idx & 3) * 8;
            gload_lds16(Abase + row * 512 + k0 + kel, &As[idx * 8]);
            gload_lds16(Bbase + row * 512 + k0 + kel, &Bs[idx * 8]);
        }
        __syncthreads();

        short8 af[4], bfr[4];
#pragma unroll
        for (int m = 0; m < 4; m++)
            af[m] = *(const short8*)&As[(wm * 64 + m * 16 + (lane & 15)) * 32 + (lane >> 4) * 8];
#pragma unroll
        for (int n = 0; n < 4; n++)
            bfr[n] = *(const short8*)&Bs[(wn * 64 + n * 16 + (lane & 15)) * 32 + (lane >> 4) * 8];
#pragma unroll
        for (int m = 0; m < 4; m++)
#pragma unroll
            for (int n = 0; n < 4; n++)
                acc[m][n] = __builtin_amdgcn_mfma_f32_16x16x32_bf16(af[m], bfr[n], acc[m][n], 0, 0, 0);
        __syncthreads();
    }

    // epilogue: C/D mapping col=lane&15, row=(lane>>4)*4+j (verified)
    const int r0 = bm * 128 + wm * 64;
    const int c0 = bn * 128 + wn * 64;
#pragma unroll
    for (int m = 0; m < 4; m++) {
#pragma unroll
        for (int n = 0; n < 4; n++) {
            int col = c0 + n * 16 + (lane & 15);
            float bv = bias[col];
#pragma unroll
            for (int j = 0; j < 4; j++) {
                int row = r0 + m * 16 + (lane >> 4) * 4 + j;
                size_t off = (size_t)row * N + col;
                float v = acc[m][n][j] + bv;
                if (EPI == 0) {
                    ((unsigned short*)Cout)[off] = f2bf(v);
                } else {
                    ((float*)Cout)[off] = v + resid[off];
                }
            }
        }
    }
}

// ---------------------------------------------------------------- per-token head-axis attention
// QKV [NTOK,1536] bf16 (Q:0-511, K:512-1023, V:1024-1535; head h = col/128).
// One wave per token; lane l owns dims {2l, 2l+1}.
__global__ __launch_bounds__(256) void attn_kernel(const unsigned short* __restrict__ qkv,
                                                   unsigned short* __restrict__ out) {
    const int tok = blockIdx.x * 4 + (threadIdx.x >> 6);
    const int lane = threadIdx.x & 63;
    const unsigned short* base = qkv + (size_t)tok * QKVN;

    float q[4][2], k[4][2], v[4][2];
#pragma unroll
    for (int h = 0; h < 4; h++) {
        unsigned int uq = *(const unsigned int*)(base + h * 128 + 2 * lane);
        unsigned int uk = *(const unsigned int*)(base + 512 + h * 128 + 2 * lane);
        unsigned int uv = *(const unsigned int*)(base + 1024 + h * 128 + 2 * lane);
        q[h][0] = bf2f((unsigned short)(uq & 0xffff)); q[h][1] = bf2f((unsigned short)(uq >> 16));
        k[h][0] = bf2f((unsigned short)(uk & 0xffff)); k[h][1] = bf2f((unsigned short)(uk >> 16));
        v[h][0] = bf2f((unsigned short)(uv & 0xffff)); v[h][1] = bf2f((unsigned short)(uv >> 16));
    }

    float s[4][4];
#pragma unroll
    for (int h = 0; h < 4; h++)
#pragma unroll
        for (int tt = 0; tt < 4; tt++)
            s[h][tt] = q[h][0] * k[tt][0] + q[h][1] * k[tt][1];

    // butterfly-reduce all 16 dot products across 64 lanes
#pragma unroll
    for (int mask = 1; mask < 64; mask <<= 1) {
#pragma unroll
        for (int h = 0; h < 4; h++)
#pragma unroll
            for (int tt = 0; tt < 4; tt++)
                s[h][tt] += __shfl_xor(s[h][tt], mask, 64);
    }

    const float scale = 0.08838834764831845f;  // 1/sqrt(128)
    float p[4][4];
#pragma unroll
    for (int h = 0; h < 4; h++) {
        float m0 = fmaxf(fmaxf(s[h][0], s[h][1]), fmaxf(s[h][2], s[h][3])) * scale;
        float sum = 0.f;
#pragma unroll
        for (int tt = 0; tt < 4; tt++) { p[h][tt] = __expf(s[h][tt] * scale - m0); sum += p[h][tt]; }
        float r = __frcp_rn(sum);
#pragma unroll
        for (int tt = 0; tt < 4; tt++) p[h][tt] *= r;
    }

#pragma unroll
    for (int h = 0; h < 4; h++) {
        float o0 = 0.f, o1 = 0.f;
#pragma unroll
        for (int tt = 0; tt < 4; tt++) { o0 += p[h][tt] * v[tt][0]; o1 += p[h][tt] * v[tt][1]; }
        unsigned int packed = (unsigned int)f2bf(o0) | ((unsigned int)f2bf(o1) << 16);
        *(unsigned int*)(out + (size_t)tok * 512 + h * 128 + 2 * lane) = packed;
    }
}

// ---------------------------------------------------------------- in-place LayerNorm on d_out
__global__ __launch_bounds__(256) void ln_kernel(float* __restrict__ y,
                                                 const float* __restrict__ g,
                                                 const float* __restrict__ b) {
    const int row = blockIdx.x * 4 + (threadIdx.x >> 6);
    const int lane = threadIdx.x & 63;
    float* p = y + (size_t)row * 512;

    float4_t a = *(float4_t*)(p + lane * 4);
    float4_t c = *(float4_t*)(p + 256 + lane * 4);

    float s = a[0] + a[1] + a[2] + a[3] + c[0] + c[1] + c[2] + c[3];
    float s2 = a[0]*a[0] + a[1]*a[1] + a[2]*a[2] + a[3]*a[3]
             + c[0]*c[0] + c[1]*c[1] + c[2]*c[2] + c[3]*c[3];
#pragma unroll
    for (int mask = 1; mask < 64; mask <<= 1) {
        s += __shfl_xor(s, mask, 64);
        s2 += __shfl_xor(s2, mask, 64);
    }
    float mu = s * (1.f / 512.f);
    float var = s2 * (1.f / 512.f) - mu * mu;
    float inv = rsqrtf(var + LN_EPS);

    float4_t ga = *(const float4_t*)(g + lane * 4);
    float4_t gb = *(const float4_t*)(g + 256 + lane * 4);
    float4_t ba = *(const float4_t*)(b + lane * 4);
    float4_t bb = *(const float4_t*)(b + 256 + lane * 4);
#pragma unroll
    for (int j = 0; j < 4; j++) {
        a[j] = (a[j] - mu) * inv * ga[j] + ba[j];
        c[j] = (c[j] - mu) * inv * gb[j] + bb[j];
    }
    *(float4_t*)(p + lane * 4) = a;
    *(float4_t*)(p + 256 + lane * 4) = c;
}

// ---------------------------------------------------------------- launch
extern "C" void kernel_launch(void* const* d_in, const int* in_sizes, int n_in,
                              void* d_out, int out_size, void* d_ws, size_t ws_size,
                              hipStream_t stream) {
    const float* x   = (const float*)d_in[0];
    const float* wq  = (const float*)d_in[1];
    const float* bq  = (const float*)d_in[2];
    const float* wk  = (const float*)d_in[3];
    const float* bk  = (const float*)d_in[4];
    const float* wv  = (const float*)d_in[5];
    const float* bv  = (const float*)d_in[6];
    const float* wo  = (const float*)d_in[7];
    const float* bo  = (const float*)d_in[8];
    const float* lng = (const float*)d_in[9];
    const float* lnb = (const float*)d_in[10];

    // workspace layout (total ~338 MB)
    char* ws = (char*)d_ws;
    unsigned short* Xb   = (unsigned short*)(ws);                 //  67,108,864  x bf16
    unsigned short* Wqkv = (unsigned short*)(ws + 67108864);      //   1,572,864  [1536,512] bf16
    unsigned short* Wob  = (unsigned short*)(ws + 68681728);      //     524,288  [512,512]  bf16
    float*          Bqkv = (float*)        (ws + 69206016);       //       6,144  [1536] f32
    unsigned short* QKV  = (unsigned short*)(ws + 69212160);      // 201,326,592  [N,1536] bf16
    unsigned short* AO   = (unsigned short*)(ws + 270538752);     //  67,108,864  [N,512]  bf16
    float* Y = (float*)d_out;

    cast_x_kernel<<<2048, 256, 0, stream>>>(x, Xb, NTOK * 512 / 8);
    prep_w_kernel<<<1024, 256, 0, stream>>>(wq, wk, wv, wo, bq, bk, bv, Wqkv, Wob, Bqkv);

    // QKV projection: [65536,512] x [1536,512]^T -> bf16 [65536,1536]
    gemm_bt_kernel<0><<<(NTOK / 128) * (QKVN / 128), 256, 0, stream>>>(Xb, Wqkv, Bqkv, nullptr, QKV, QKVN);

    // per-token 4x4 head-axis attention -> bf16 [65536,512]
    attn_kernel<<<NTOK / 4, 256, 0, stream>>>(QKV, AO);

    // O projection + bias + residual -> fp32 d_out
    gemm_bt_kernel<1><<<(NTOK / 128) * (DMODEL / 128), 256, 0, stream>>>(AO, Wob, bo, x, Y, DMODEL);

    // in-place LayerNorm
    ln_kernel<<<NTOK / 4, 256, 0, stream>>>(Y, lng, lnb);
}